// Round 1
// baseline (617.981 us; speedup 1.0000x reference)
//
#include <hip/hip_runtime.h>

#define NT 8192      // tokens = B*S
#define DIM 1024     // D
#define FDIM 4096    // F
#define NEXP 8       // experts

typedef __attribute__((ext_vector_type(8))) short bfx8;   // 8 bf16 (4 VGPRs)
typedef __attribute__((ext_vector_type(4))) float fx4;    // MFMA accumulator

__device__ __forceinline__ unsigned short f2bf(float f) {
  union { float f; unsigned u; } v; v.f = f;
  unsigned u = v.u;
  unsigned r = u + 0x7FFFu + ((u >> 16) & 1u);   // round-to-nearest-even
  return (unsigned short)(r >> 16);
}

// ---------------- zero counters ----------------
__global__ void k_zero(int* __restrict__ counts) {
  if (threadIdx.x < NEXP) counts[threadIdx.x] = 0;
}

// ---------------- routing: argmax affinity + alpha ----------------
__global__ __launch_bounds__(256) void k_routing(
    const float* __restrict__ x, const float* __restrict__ cent,
    int* __restrict__ eid, float* __restrict__ alpha, int* __restrict__ counts)
{
  const int t = blockIdx.x, tid = threadIdx.x;
  const float4 xv = ((const float4*)(x + (size_t)t * DIM))[tid];
  float acc[NEXP];
#pragma unroll
  for (int e = 0; e < NEXP; ++e) {
    const float4 cv = ((const float4*)(cent + (size_t)e * DIM))[tid];
    acc[e] = xv.x * cv.x + xv.y * cv.y + xv.z * cv.z + xv.w * cv.w;
  }
#pragma unroll
  for (int off = 32; off > 0; off >>= 1)
#pragma unroll
    for (int e = 0; e < NEXP; ++e) acc[e] += __shfl_down(acc[e], off);
  __shared__ float part[4][NEXP];
  const int lane = tid & 63, w = tid >> 6;
  if (lane == 0)
#pragma unroll
    for (int e = 0; e < NEXP; ++e) part[w][e] = acc[e];
  __syncthreads();
  if (tid == 0) {
    int best = 0; float bv = -1e30f;
#pragma unroll
    for (int e = 0; e < NEXP; ++e) {
      float v = part[0][e] + part[1][e] + part[2][e] + part[3][e];
      if (v > bv) { bv = v; best = e; }   // strict > keeps first max (matches argmax)
    }
    eid[t] = best;
    alpha[t] = 1.0f / (1.0f + expf(-bv));
    atomicAdd(&counts[best], 1);
  }
}

// ---------------- exclusive scan of 8 counts ----------------
__global__ void k_scan(const int* __restrict__ counts, int* __restrict__ bs, int* __restrict__ cur) {
  if (threadIdx.x == 0) {
    int s = 0;
    for (int e = 0; e < NEXP; ++e) { bs[e] = s; cur[e] = s; s += counts[e]; }
  }
}

// ---------------- LayerNorm + counting-sort scatter (bf16) ----------------
__global__ __launch_bounds__(256) void k_ln_scatter(
    const float* __restrict__ x, const float* __restrict__ g, const float* __restrict__ b,
    const int* __restrict__ eid, int* __restrict__ cur,
    int* __restrict__ row_tok, unsigned short* __restrict__ xln)
{
  const int t = blockIdx.x, tid = threadIdx.x;
  const float4 xv = ((const float4*)(x + (size_t)t * DIM))[tid];
  float s = xv.x + xv.y + xv.z + xv.w;
  float ss = xv.x * xv.x + xv.y * xv.y + xv.z * xv.z + xv.w * xv.w;
#pragma unroll
  for (int off = 32; off > 0; off >>= 1) { s += __shfl_down(s, off); ss += __shfl_down(ss, off); }
  __shared__ float ps[4], pss[4];
  __shared__ float smu, srstd;
  __shared__ int spos, se;
  const int lane = tid & 63, w = tid >> 6;
  if (lane == 0) { ps[w] = s; pss[w] = ss; }
  __syncthreads();
  if (tid == 0) {
    const float sum = ps[0] + ps[1] + ps[2] + ps[3];
    const float sq  = pss[0] + pss[1] + pss[2] + pss[3];
    const float mu = sum * (1.0f / DIM);
    const float var = sq * (1.0f / DIM) - mu * mu;
    smu = mu; srstd = rsqrtf(var + 1e-5f);
    const int e = eid[t]; se = e;
    const int pos = atomicAdd(&cur[e], 1);
    row_tok[pos] = t;
    spos = pos;
  }
  __syncthreads();
  const float mu = smu, rstd = srstd;
  const int e = se, pos = spos;
  const float4 gv = ((const float4*)(g + (size_t)e * DIM))[tid];
  const float4 bv = ((const float4*)(b + (size_t)e * DIM))[tid];
  ushort4 o;
  o.x = f2bf((xv.x - mu) * rstd * gv.x + bv.x);
  o.y = f2bf((xv.y - mu) * rstd * gv.y + bv.y);
  o.z = f2bf((xv.z - mu) * rstd * gv.z + bv.z);
  o.w = f2bf((xv.w - mu) * rstd * gv.w + bv.w);
  ((ushort4*)(xln + (size_t)pos * DIM))[tid] = o;
}

// ---------------- transpose fp32 [R][C] -> bf16 [C][R] per expert ----------------
__global__ __launch_bounds__(256) void k_transpose(
    const float* __restrict__ in, unsigned short* __restrict__ outT, int R, int C)
{
  __shared__ float tile[32][33];
  const int e = blockIdx.z;
  const float* src = in + (size_t)e * R * C;
  unsigned short* dst = outT + (size_t)e * R * C;
  const int tx = threadIdx.x & 31, ty = threadIdx.x >> 5;
  const int r0 = blockIdx.y * 32, c0 = blockIdx.x * 32;
#pragma unroll
  for (int j = 0; j < 4; ++j)
    tile[ty + j * 8][tx] = src[(size_t)(r0 + ty + j * 8) * C + c0 + tx];
  __syncthreads();
#pragma unroll
  for (int j = 0; j < 4; ++j)
    dst[(size_t)(c0 + ty + j * 8) * R + r0 + tx] = f2bf(tile[tx][ty + j * 8]);
}

// ---------------- grouped MFMA GEMM, 128x128 tile, BK=32, 4 waves ----------------
// A: [NT][K] bf16 (expert-sorted rows). Bt: [E][N][K] bf16 (K-major).
// FIRST:  H = relu(A*W1 + b1) -> bf16 [NT][F]
// !FIRST: out[tok] = x[tok] + alpha[tok] * (A*W2 + b2), scattered by row_tok
template<int K, int N, bool FIRST>
__global__ __launch_bounds__(256) void k_gemm(
    const unsigned short* __restrict__ A,
    const unsigned short* __restrict__ Bt,
    const float* __restrict__ bias,
    const int* __restrict__ bs, const int* __restrict__ counts,
    unsigned short* __restrict__ Hout,
    const int* __restrict__ row_tok, const float* __restrict__ alpha,
    const float* __restrict__ xin, float* __restrict__ out)
{
  const int e = blockIdx.z;
  const int cnt = counts[e];
  const int m0 = blockIdx.y * 128;
  if (m0 >= cnt) return;
  const int n0 = blockIdx.x * 128;
  const int rbase = bs[e];

  // row stride 40 ushorts = 80B (16B-aligned, 2-way bank aliasing = free)
  __shared__ unsigned short lA[128 * 40];
  __shared__ unsigned short lB[128 * 40];

  const int tid = threadIdx.x;
  const int lane = tid & 63, wv = tid >> 6;
  const int wm = (wv >> 1) * 64, wn = (wv & 1) * 64;
  const int lr = lane & 15, lg = lane >> 4;

  fx4 acc[4][4] = {};

  const unsigned short* Bte = Bt + (size_t)e * N * K;

  for (int k0 = 0; k0 < K; k0 += 32) {
#pragma unroll
    for (int p = 0; p < 2; ++p) {
      const int c = tid + p * 256;          // 0..511 chunks of 16B
      const int row = c >> 2, kq = c & 3;
      uint4 va = make_uint4(0u, 0u, 0u, 0u);
      if (m0 + row < cnt)
        va = *(const uint4*)(A + (size_t)(rbase + m0 + row) * K + k0 + kq * 8);
      *(uint4*)(&lA[row * 40 + kq * 8]) = va;
      const uint4 vb = *(const uint4*)(Bte + (size_t)(n0 + row) * K + k0 + kq * 8);
      *(uint4*)(&lB[row * 40 + kq * 8]) = vb;
    }
    __syncthreads();
    bfx8 af[4], bf[4];
#pragma unroll
    for (int i = 0; i < 4; ++i)
      af[i] = *(const bfx8*)(&lA[(wm + i * 16 + lr) * 40 + lg * 8]);
#pragma unroll
    for (int j = 0; j < 4; ++j)
      bf[j] = *(const bfx8*)(&lB[(wn + j * 16 + lr) * 40 + lg * 8]);
#pragma unroll
    for (int i = 0; i < 4; ++i)
#pragma unroll
      for (int j = 0; j < 4; ++j)
        acc[i][j] = __builtin_amdgcn_mfma_f32_16x16x32_bf16(af[i], bf[j], acc[i][j], 0, 0, 0);
    __syncthreads();
  }

  if constexpr (FIRST) {
#pragma unroll
    for (int i = 0; i < 4; ++i) {
#pragma unroll
      for (int r = 0; r < 4; ++r) {
        const int rl = wm + i * 16 + lg * 4 + r;
        if (m0 + rl >= cnt) continue;
        unsigned short* hrow = Hout + (size_t)(rbase + m0 + rl) * N;
#pragma unroll
        for (int j = 0; j < 4; ++j) {
          const int col = n0 + wn + j * 16 + lr;
          float v = acc[i][j][r] + bias[e * N + col];
          v = v > 0.f ? v : 0.f;
          hrow[col] = f2bf(v);
        }
      }
    }
  } else {
#pragma unroll
    for (int i = 0; i < 4; ++i) {
#pragma unroll
      for (int r = 0; r < 4; ++r) {
        const int rl = wm + i * 16 + lg * 4 + r;
        if (m0 + rl >= cnt) continue;
        const int tok = row_tok[rbase + m0 + rl];
        const float al = alpha[tok];
        const float* xrow = xin + (size_t)tok * N;
        float* orow = out + (size_t)tok * N;
#pragma unroll
        for (int j = 0; j < 4; ++j) {
          const int col = n0 + wn + j * 16 + lr;
          orow[col] = xrow[col] + al * (acc[i][j][r] + bias[e * N + col]);
        }
      }
    }
  }
}

extern "C" void kernel_launch(void* const* d_in, const int* in_sizes, int n_in,
                              void* d_out, int out_size, void* d_ws, size_t ws_size,
                              hipStream_t stream)
{
  const float* x    = (const float*)d_in[0];
  const float* cent = (const float*)d_in[1];
  const float* ln_g = (const float*)d_in[2];
  const float* ln_b = (const float*)d_in[3];
  const float* w1   = (const float*)d_in[4];
  const float* b1   = (const float*)d_in[5];
  const float* w2   = (const float*)d_in[6];
  const float* b2   = (const float*)d_in[7];
  float* out = (float*)d_out;

  char* ws = (char*)d_ws;
  unsigned short* xln  = (unsigned short*)(ws);                          // 16 MB [NT][DIM] bf16
  unsigned short* hbuf = (unsigned short*)(ws + (16ull << 20));          // 64 MB [NT][FDIM] bf16
  unsigned short* w1t  = (unsigned short*)(ws + (80ull << 20));          // 64 MB [E][F][D] bf16
  unsigned short* w2t  = (unsigned short*)(ws + (144ull << 20));         // 64 MB [E][D][F] bf16
  char* tail = ws + (208ull << 20);
  int*   eid    = (int*)(tail);
  float* alpha  = (float*)(tail + 32768);
  int*   rowtok = (int*)(tail + 65536);
  int*   counts = (int*)(tail + 98304);
  int*   basep  = counts + 16;
  int*   cur    = counts + 32;

  k_zero<<<1, 64, 0, stream>>>(counts);
  k_routing<<<NT, 256, 0, stream>>>(x, cent, eid, alpha, counts);
  k_scan<<<1, 1, 0, stream>>>(counts, basep, cur);
  k_ln_scatter<<<NT, 256, 0, stream>>>(x, ln_g, ln_b, eid, cur, rowtok, xln);
  k_transpose<<<dim3(FDIM / 32, DIM / 32, NEXP), 256, 0, stream>>>(w1, w1t, DIM, FDIM);
  k_transpose<<<dim3(DIM / 32, FDIM / 32, NEXP), 256, 0, stream>>>(w2, w2t, FDIM, DIM);
  k_gemm<DIM, FDIM, true><<<dim3(FDIM / 128, NT / 128, NEXP), 256, 0, stream>>>(
      xln, w1t, b1, basep, counts, hbuf, nullptr, nullptr, nullptr, nullptr);
  k_gemm<FDIM, DIM, false><<<dim3(DIM / 128, NT / 128, NEXP), 256, 0, stream>>>(
      hbuf, w2t, b2, basep, counts, nullptr, rowtok, alpha, x, out);
}

// Round 2
// 535.999 us; speedup vs baseline: 1.1530x; 1.1530x over previous
//
#include <hip/hip_runtime.h>

#define NT 8192      // tokens = B*S
#define DIM 1024     // D
#define FDIM 4096    // F
#define NEXP 8       // experts

typedef __attribute__((ext_vector_type(8))) short bfx8;   // 8 bf16 (4 VGPRs)
typedef __attribute__((ext_vector_type(4))) float fx4;    // MFMA accumulator

__device__ __forceinline__ unsigned short f2bf(float f) {
  union { float f; unsigned u; } v; v.f = f;
  unsigned u = v.u;
  unsigned r = u + 0x7FFFu + ((u >> 16) & 1u);   // round-to-nearest-even
  return (unsigned short)(r >> 16);
}

__device__ __forceinline__ void gload16(const void* g, void* l) {
  __builtin_amdgcn_global_load_lds(
      (const __attribute__((address_space(1))) unsigned int*)g,
      (__attribute__((address_space(3))) unsigned int*)l, 16, 0, 0);
}

// ---------------- zero counters ----------------
__global__ void k_zero(int* __restrict__ counts) {
  if (threadIdx.x < NEXP) counts[threadIdx.x] = 0;
}

// ---------------- routing: argmax affinity + alpha ----------------
__global__ __launch_bounds__(256) void k_routing(
    const float* __restrict__ x, const float* __restrict__ cent,
    int* __restrict__ eid, float* __restrict__ alpha, int* __restrict__ counts)
{
  const int t = blockIdx.x, tid = threadIdx.x;
  const float4 xv = ((const float4*)(x + (size_t)t * DIM))[tid];
  float acc[NEXP];
#pragma unroll
  for (int e = 0; e < NEXP; ++e) {
    const float4 cv = ((const float4*)(cent + (size_t)e * DIM))[tid];
    acc[e] = xv.x * cv.x + xv.y * cv.y + xv.z * cv.z + xv.w * cv.w;
  }
#pragma unroll
  for (int off = 32; off > 0; off >>= 1)
#pragma unroll
    for (int e = 0; e < NEXP; ++e) acc[e] += __shfl_down(acc[e], off);
  __shared__ float part[4][NEXP];
  const int lane = tid & 63, w = tid >> 6;
  if (lane == 0)
#pragma unroll
    for (int e = 0; e < NEXP; ++e) part[w][e] = acc[e];
  __syncthreads();
  if (tid == 0) {
    int best = 0; float bv = -1e30f;
#pragma unroll
    for (int e = 0; e < NEXP; ++e) {
      float v = part[0][e] + part[1][e] + part[2][e] + part[3][e];
      if (v > bv) { bv = v; best = e; }   // strict > keeps first max (matches argmax)
    }
    eid[t] = best;
    alpha[t] = 1.0f / (1.0f + expf(-bv));
    atomicAdd(&counts[best], 1);
  }
}

// ---------------- exclusive scan of 8 counts ----------------
__global__ void k_scan(const int* __restrict__ counts, int* __restrict__ bs, int* __restrict__ cur) {
  if (threadIdx.x == 0) {
    int s = 0;
    for (int e = 0; e < NEXP; ++e) { bs[e] = s; cur[e] = s; s += counts[e]; }
  }
}

// ---------------- LayerNorm + counting-sort scatter (bf16) ----------------
__global__ __launch_bounds__(256) void k_ln_scatter(
    const float* __restrict__ x, const float* __restrict__ g, const float* __restrict__ b,
    const int* __restrict__ eid, int* __restrict__ cur,
    int* __restrict__ row_tok, unsigned short* __restrict__ xln)
{
  const int t = blockIdx.x, tid = threadIdx.x;
  const float4 xv = ((const float4*)(x + (size_t)t * DIM))[tid];
  float s = xv.x + xv.y + xv.z + xv.w;
  float ss = xv.x * xv.x + xv.y * xv.y + xv.z * xv.z + xv.w * xv.w;
#pragma unroll
  for (int off = 32; off > 0; off >>= 1) { s += __shfl_down(s, off); ss += __shfl_down(ss, off); }
  __shared__ float ps[4], pss[4];
  __shared__ float smu, srstd;
  __shared__ int spos, se;
  const int lane = tid & 63, w = tid >> 6;
  if (lane == 0) { ps[w] = s; pss[w] = ss; }
  __syncthreads();
  if (tid == 0) {
    const float sum = ps[0] + ps[1] + ps[2] + ps[3];
    const float sq  = pss[0] + pss[1] + pss[2] + pss[3];
    const float mu = sum * (1.0f / DIM);
    const float var = sq * (1.0f / DIM) - mu * mu;
    smu = mu; srstd = rsqrtf(var + 1e-5f);
    const int e = eid[t]; se = e;
    const int pos = atomicAdd(&cur[e], 1);
    row_tok[pos] = t;
    spos = pos;
  }
  __syncthreads();
  const float mu = smu, rstd = srstd;
  const int e = se, pos = spos;
  const float4 gv = ((const float4*)(g + (size_t)e * DIM))[tid];
  const float4 bv = ((const float4*)(b + (size_t)e * DIM))[tid];
  ushort4 o;
  o.x = f2bf((xv.x - mu) * rstd * gv.x + bv.x);
  o.y = f2bf((xv.y - mu) * rstd * gv.y + bv.y);
  o.z = f2bf((xv.z - mu) * rstd * gv.z + bv.z);
  o.w = f2bf((xv.w - mu) * rstd * gv.w + bv.w);
  ((ushort4*)(xln + (size_t)pos * DIM))[tid] = o;
}

// ---------------- transpose fp32 [R][C] -> bf16 [C][R], 64x64 tiles ----------------
__global__ __launch_bounds__(256) void k_transpose(
    const float* __restrict__ in, unsigned short* __restrict__ outT, int R, int C)
{
  __shared__ float tile[64][68];   // stride 68 floats: float4-aligned rows
  const int e = blockIdx.z;
  const float* src = in + (size_t)e * R * C;
  unsigned short* dst = outT + (size_t)e * R * C;
  const int r0 = blockIdx.y * 64, c0 = blockIdx.x * 64;
  const int t = threadIdx.x;
  {
    const int cx = t & 15, ry = t >> 4;          // cx: float4 column, ry: row 0..15
#pragma unroll
    for (int j = 0; j < 4; ++j) {
      const int row = ry + j * 16;
      const float4 v = *(const float4*)(src + (size_t)(r0 + row) * C + c0 + cx * 4);
      *(float4*)&tile[row][cx * 4] = v;
    }
  }
  __syncthreads();
  {
    const int rx = t & 7, cy = t >> 3;           // rx: 8-row chunk, cy: col 0..31
#pragma unroll
    for (int j = 0; j < 2; ++j) {
      const int c = cy + j * 32;
      unsigned short o[8];
#pragma unroll
      for (int u = 0; u < 8; ++u) o[u] = f2bf(tile[rx * 8 + u][c]);
      *(uint4*)(dst + (size_t)(c0 + c) * R + r0 + rx * 8) = *(const uint4*)o;
    }
  }
}

// ---------------- grouped MFMA GEMM, 128x128 tile, BK=32, 4 waves ----------------
// m97 structure: global_load_lds width-16 staging into linear [128][32] LDS.
// A: [NT][K] bf16 (expert-sorted rows). Bt: [E][N][K] bf16 (K-major).
// FIRST:  H = relu(A*W1 + b1) -> bf16 [NT][F]
// !FIRST: out[tok] = x[tok] + alpha[tok] * (A*W2 + b2), scattered by row_tok
template<int K, int N, bool FIRST>
__global__ __launch_bounds__(256) void k_gemm(
    const unsigned short* __restrict__ A,
    const unsigned short* __restrict__ Bt,
    const float* __restrict__ bias,
    const int* __restrict__ bs, const int* __restrict__ counts,
    unsigned short* __restrict__ Hout,
    const int* __restrict__ row_tok, const float* __restrict__ alpha,
    const float* __restrict__ xin, float* __restrict__ out)
{
  const int e = blockIdx.z;
  const int cnt = counts[e];
  const int m0 = blockIdx.y * 128;
  if (m0 >= cnt) return;
  const int n0 = blockIdx.x * 128;
  const int rbase = bs[e];

  __shared__ unsigned short lA[128 * 32];   // linear, no pad (global_load_lds dest)
  __shared__ unsigned short lB[128 * 32];

  const int tid = threadIdx.x;
  const int lane = tid & 63, wv = tid >> 6;
  const int wm = (wv >> 1) * 64, wn = (wv & 1) * 64;
  const int lr = lane & 15, lg = lane >> 4;

  fx4 acc[4][4] = {};

  const unsigned short* Bte = Bt + (size_t)e * N * K;

  // staging geometry: instruction p (0/1), chunk g = p*256+tid covers
  // row = g>>2, k-offset = (g&3)*8; LDS dest is linear: elem offset 8*g.
  const unsigned short* aP[2];
  const unsigned short* bP[2];
  unsigned short* lAd[2];
  unsigned short* lBd[2];
#pragma unroll
  for (int p = 0; p < 2; ++p) {
    const int g = p * 256 + tid;
    const int row = g >> 2, kq = (g & 3) * 8;
    int ar = rbase + m0 + row;
    ar = ar < NT ? ar : NT - 1;               // clamp: garbage rows masked at epilogue
    aP[p] = A + (size_t)ar * K + kq;
    bP[p] = Bte + (size_t)(n0 + row) * K + kq;
    lAd[p] = &lA[(p * 4 + wv) * 512];         // wave-uniform base + lane*16B
    lBd[p] = &lB[(p * 4 + wv) * 512];
  }

  for (int k0 = 0; k0 < K; k0 += 32) {
    gload16(aP[0] + k0, lAd[0]);
    gload16(aP[1] + k0, lAd[1]);
    gload16(bP[0] + k0, lBd[0]);
    gload16(bP[1] + k0, lBd[1]);
    __syncthreads();                          // compiler inserts vmcnt(0) drain
    bfx8 af[4], bf[4];
#pragma unroll
    for (int i = 0; i < 4; ++i)
      af[i] = *(const bfx8*)(&lA[(wm + i * 16 + lr) * 32 + lg * 8]);
#pragma unroll
    for (int j = 0; j < 4; ++j)
      bf[j] = *(const bfx8*)(&lB[(wn + j * 16 + lr) * 32 + lg * 8]);
#pragma unroll
    for (int i = 0; i < 4; ++i)
#pragma unroll
      for (int j = 0; j < 4; ++j)
        acc[i][j] = __builtin_amdgcn_mfma_f32_16x16x32_bf16(af[i], bf[j], acc[i][j], 0, 0, 0);
    __syncthreads();
  }

  if constexpr (FIRST) {
#pragma unroll
    for (int i = 0; i < 4; ++i) {
#pragma unroll
      for (int r = 0; r < 4; ++r) {
        const int rl = wm + i * 16 + lg * 4 + r;
        if (m0 + rl >= cnt) continue;
        unsigned short* hrow = Hout + (size_t)(rbase + m0 + rl) * N;
#pragma unroll
        for (int j = 0; j < 4; ++j) {
          const int col = n0 + wn + j * 16 + lr;
          float v = acc[i][j][r] + bias[e * N + col];
          v = v > 0.f ? v : 0.f;
          hrow[col] = f2bf(v);
        }
      }
    }
  } else {
#pragma unroll
    for (int i = 0; i < 4; ++i) {
#pragma unroll
      for (int r = 0; r < 4; ++r) {
        const int rl = wm + i * 16 + lg * 4 + r;
        if (m0 + rl >= cnt) continue;
        const int tok = row_tok[rbase + m0 + rl];
        const float al = alpha[tok];
        const float* xrow = xin + (size_t)tok * N;
        float* orow = out + (size_t)tok * N;
#pragma unroll
        for (int j = 0; j < 4; ++j) {
          const int col = n0 + wn + j * 16 + lr;
          orow[col] = xrow[col] + al * (acc[i][j][r] + bias[e * N + col]);
        }
      }
    }
  }
}

extern "C" void kernel_launch(void* const* d_in, const int* in_sizes, int n_in,
                              void* d_out, int out_size, void* d_ws, size_t ws_size,
                              hipStream_t stream)
{
  const float* x    = (const float*)d_in[0];
  const float* cent = (const float*)d_in[1];
  const float* ln_g = (const float*)d_in[2];
  const float* ln_b = (const float*)d_in[3];
  const float* w1   = (const float*)d_in[4];
  const float* b1   = (const float*)d_in[5];
  const float* w2   = (const float*)d_in[6];
  const float* b2   = (const float*)d_in[7];
  float* out = (float*)d_out;

  char* ws = (char*)d_ws;
  unsigned short* xln  = (unsigned short*)(ws);                          // 16 MB [NT][DIM] bf16
  unsigned short* hbuf = (unsigned short*)(ws + (16ull << 20));          // 64 MB [NT][FDIM] bf16
  unsigned short* w1t  = (unsigned short*)(ws + (80ull << 20));          // 64 MB [E][F][D] bf16
  unsigned short* w2t  = (unsigned short*)(ws + (144ull << 20));         // 64 MB [E][D][F] bf16
  char* tail = ws + (208ull << 20);
  int*   eid    = (int*)(tail);
  float* alpha  = (float*)(tail + 32768);
  int*   rowtok = (int*)(tail + 65536);
  int*   counts = (int*)(tail + 98304);
  int*   basep  = counts + 16;
  int*   cur    = counts + 32;

  k_zero<<<1, 64, 0, stream>>>(counts);
  k_routing<<<NT, 256, 0, stream>>>(x, cent, eid, alpha, counts);
  k_scan<<<1, 1, 0, stream>>>(counts, basep, cur);
  k_ln_scatter<<<NT, 256, 0, stream>>>(x, ln_g, ln_b, eid, cur, rowtok, xln);
  k_transpose<<<dim3(FDIM / 64, DIM / 64, NEXP), 256, 0, stream>>>(w1, w1t, DIM, FDIM);
  k_transpose<<<dim3(DIM / 64, FDIM / 64, NEXP), 256, 0, stream>>>(w2, w2t, FDIM, DIM);
  k_gemm<DIM, FDIM, true><<<dim3(FDIM / 128, NT / 128, NEXP), 256, 0, stream>>>(
      xln, w1t, b1, basep, counts, hbuf, nullptr, nullptr, nullptr, nullptr);
  k_gemm<FDIM, DIM, false><<<dim3(DIM / 128, NT / 128, NEXP), 256, 0, stream>>>(
      hbuf, w2t, b2, basep, counts, nullptr, rowtok, alpha, x, out);
}